// Round 11
// baseline (206.573 us; speedup 1.0000x reference)
//
#include <hip/hip_runtime.h>
#include <cstdint>
#include <cstddef>

typedef __bf16 bf16;
typedef __bf16 bf16x4_t __attribute__((ext_vector_type(4)));
typedef __bf16 bf16x8_t __attribute__((ext_vector_type(8)));
typedef float  f32x4_t  __attribute__((ext_vector_type(4)));

#define GLD_LDS16(g, l)                                                              \
  __builtin_amdgcn_global_load_lds((const __attribute__((address_space(1))) void*)(g), \
                                   (__attribute__((address_space(3))) void*)(l), 16, 0, 0)

#define S_WAITCNT_VMCNT(N) asm volatile("s_waitcnt vmcnt(" #N ")" ::: "memory")
#define S_BARRIER() asm volatile("s_barrier" ::: "memory")

// ---------------------------------------------------------------------------
// fp32 -> bf16 conversion, grid-stride, 16B stores (R18; at HBM roofline).
// ---------------------------------------------------------------------------
__global__ __launch_bounds__(256) void cvt_kernel(
    const float* __restrict__ q, const float* __restrict__ k, const float* __restrict__ v,
    const float* __restrict__ wq, const float* __restrict__ wk, const float* __restrict__ wv,
    const float* __restrict__ wo,
    bf16* __restrict__ qb, bf16* __restrict__ kb, bf16* __restrict__ vb,
    bf16* __restrict__ wqb, bf16* __restrict__ wkb, bf16* __restrict__ wvb,
    bf16* __restrict__ wob)
{
  const float* src; bf16* dst; int n;
  switch (blockIdx.y) {
    case 0: src = q;  dst = qb;  n = 4194304; break;
    case 1: src = k;  dst = kb;  n = 4194304; break;
    case 2: src = v;  dst = vb;  n = 4194304; break;
    case 3: src = wq; dst = wqb; n = 1048576; break;
    case 4: src = wk; dst = wkb; n = 1048576; break;
    case 5: src = wv; dst = wvb; n = 1048576; break;
    default: src = wo; dst = wob; n = 1048576; break;
  }
  const int nv8 = n >> 3;                      // 8-float chunks
  const int stride = gridDim.x * 256;
  const float4* s4 = (const float4*)src;
  bf16x8_t* d8 = (bf16x8_t*)dst;
  for (int i = blockIdx.x * 256 + threadIdx.x; i < nv8; i += stride) {
    const float4 f0 = s4[2 * i];
    const float4 f1 = s4[2 * i + 1];
    bf16x8_t o;
    o[0] = (bf16)f0.x; o[1] = (bf16)f0.y; o[2] = (bf16)f0.z; o[3] = (bf16)f0.w;
    o[4] = (bf16)f1.x; o[5] = (bf16)f1.y; o[6] = (bf16)f1.z; o[7] = (bf16)f1.w;
    d8[i] = o;
  }
}

// ---------------------------------------------------------------------------
// 128x128 GEMM main loop (B^T weights), used by gemm_out_k. Triple-buffered
// LDS, prefetch distance 2, vmcnt(4)+raw-barrier pipeline. SLOT8 swizzle.
// ---------------------------------------------------------------------------
__device__ __forceinline__ void gemm_core(const bf16* __restrict__ A,
                                          const bf16* __restrict__ W,
                                          int m0, int n0, bf16* smem,
                                          f32x4_t (&acc)[4][4])
{
  const int K = 1024;
  bf16* As = smem;
  bf16* Bs = smem + 12288;
  const int t = threadIdx.x;
  const int lane = t & 63, w = t >> 6;
  const int l16 = lane & 15, qd = lane >> 4;
  const int wm = (w & 1) * 64, wn = (w >> 1) * 64;

  const int p8 = t >> 3;
  const int vslot = (t & 7) ^ (p8 & 7);
  const int srow = 2 * p8 + (vslot >> 2);
  const int scc = vslot & 3;
  const bf16* ag0 = A + (size_t)(m0 + srow) * K + scc * 8;
  const bf16* ag1 = A + (size_t)(m0 + 64 + srow) * K + scc * 8;
  const bf16* wg0 = W + (size_t)(n0 + srow) * K + scc * 8;
  const bf16* wg1 = W + (size_t)(n0 + 64 + srow) * K + scc * 8;
  const int lo0 = (w * 64) * 8;
  const int lo1 = (256 + w * 64) * 8;

  const int rslot = (((l16 & 1) * 4 + qd) ^ ((l16 >> 1) & 7)) * 8;
  const int abase = (wm >> 6) * 2048 + (l16 >> 1) * 64 + rslot;
  const int bbase = (wn >> 6) * 2048 + (l16 >> 1) * 64 + rslot;

#define STAGEG(k0_, b_)                                  \
  do {                                                   \
    GLD_LDS16(ag0 + (k0_), &As[(b_) * 4096 + lo0]);      \
    GLD_LDS16(ag1 + (k0_), &As[(b_) * 4096 + lo1]);      \
    GLD_LDS16(wg0 + (k0_), &Bs[(b_) * 4096 + lo0]);      \
    GLD_LDS16(wg1 + (k0_), &Bs[(b_) * 4096 + lo1]);      \
  } while (0)

  STAGEG(0, 0);
  STAGEG(32, 1);

  for (int k0 = 0; k0 < K; k0 += 32) {
    const int it = k0 >> 5;
    const int cb = it - (it / 3) * 3;
    if (k0 + 32 < K) S_WAITCNT_VMCNT(4); else S_WAITCNT_VMCNT(0);
    S_BARRIER();
    if (k0 + 64 < K) {
      const int nb = (it + 2) - ((it + 2) / 3) * 3;
      STAGEG(k0 + 64, nb);
    }
    bf16x8_t af[4], bfg[4];
#pragma unroll
    for (int i = 0; i < 4; ++i)
      af[i] = *(const bf16x8_t*)(&As[cb * 4096 + abase + i * 512]);
#pragma unroll
    for (int j = 0; j < 4; ++j)
      bfg[j] = *(const bf16x8_t*)(&Bs[cb * 4096 + bbase + j * 512]);
#pragma unroll
    for (int i = 0; i < 4; ++i)
#pragma unroll
      for (int j = 0; j < 4; ++j)
        acc[i][j] = __builtin_amdgcn_mfma_f32_16x16x32_bf16(af[i], bfg[j], acc[i][j], 0, 0, 0);
  }
#undef STAGEG
}

// ---------------------------------------------------------------------------
// R19: Fused QKV projection retiled 256x256 -> 128x256 (BM=128, BN=256,
// 512 thr, 8 waves; wave = full 64x64 head block, wm=((w>>2)&1)*64,
// wn=(w&3)*64). Rationale: R12's 256² grid was 192 WGs = 75% machine fill,
// 1 WG/CU, zero WG-TLP (every vmcnt rendezvous exposed — R13 showed 2-WG
// co-residency is the latency hider). 128x256: grid (4,32,3)=384 WGs =
// 100% fill; LDS 3x(A 4096 + B 8192) = 72KB -> 2 WG/CU. A-reuse per strip
// unchanged (4 n-tiles) -> FETCH ~55MB. 3 gload/thread/stage -> vmcnt(3).
// Addressing stays in the verified SLOT8 family (B = 256² A-half code
// verbatim; A = single-half form). Numerics unchanged.
// ---------------------------------------------------------------------------
__global__ __launch_bounds__(512) void gemm_qkv(
    const bf16* __restrict__ qb, const bf16* __restrict__ wqb,
    const bf16* __restrict__ kb, const bf16* __restrict__ wkb,
    const bf16* __restrict__ vb, const bf16* __restrict__ wvb,
    const float* __restrict__ qnw, const float* __restrict__ knw,
    bf16* __restrict__ Qp, bf16* __restrict__ Kp, bf16* __restrict__ Vt)
{
  __shared__ bf16 smem[36864];
  const int K = 1024;
  const int z = blockIdx.z;
  const bf16 *A, *W;
  if (z == 0)      { A = qb; W = wqb; }
  else if (z == 1) { A = kb; W = wkb; }
  else             { A = vb; W = wvb; }

  const int m0 = blockIdx.y * 128, n0 = blockIdx.x * 256;
  const int t = threadIdx.x;
  const int lane = t & 63, w = t >> 6;
  const int l16 = lane & 15, qd = lane >> 4;
  const int wm = ((w >> 2) & 1) * 64, wn = (w & 3) * 64;

  bf16* As = smem;                 // 3 buffers x 4096 (128 rows x 32 k)
  bf16* Bs = smem + 12288;         // 3 buffers x 8192 (256 rows x 32 k)

  // staging writer: thread t fills 16B chunk t per block/half
  const int p8 = t >> 3;                 // row pair 0..63
  const int vslot = (t & 7) ^ (p8 & 7);
  const int srow = 2 * p8 + (vslot >> 2);
  const int scc = vslot & 3;
  const bf16* ag0 = A + (size_t)(m0 + srow) * K + scc * 8;        // A: 128 rows
  const bf16* wg0 = W + (size_t)(n0 + srow) * K + scc * 8;        // B half 0
  const bf16* wg1 = W + (size_t)(n0 + 128 + srow) * K + scc * 8;  // B half 1
  const int lo0 = t * 8;
  const int lo1 = 4096 + t * 8;

  // readers
  const int rslot = (((l16 & 1) * 4 + qd) ^ ((l16 >> 1) & 7)) * 8;
  const int abase = (((w >> 2) & 1) * 32 + (l16 >> 1)) * 64 + rslot;
  const int bbase = ((w >> 1) & 1) * 4096 + ((w & 1) * 32 + (l16 >> 1)) * 64 + rslot;

  f32x4_t acc[4][4] = {};

#define STAGEG(k0_, b_)                                  \
  do {                                                   \
    GLD_LDS16(ag0 + (k0_), &As[(b_) * 4096 + lo0]);      \
    GLD_LDS16(wg0 + (k0_), &Bs[(b_) * 8192 + lo0]);      \
    GLD_LDS16(wg1 + (k0_), &Bs[(b_) * 8192 + lo1]);      \
  } while (0)

  STAGEG(0, 0);
  STAGEG(32, 1);

  for (int kk = 0; kk < 32; ++kk) {
    const int cb = kk - (kk / 3) * 3;           // kk % 3
    if (kk < 31) S_WAITCNT_VMCNT(3); else S_WAITCNT_VMCNT(0);
    S_BARRIER();
    if (kk + 2 < 32) {
      const int nb = (kk + 2) - ((kk + 2) / 3) * 3;
      STAGEG((kk + 2) * 32, nb);
    }
    bf16x8_t af[4], bfg[4];
#pragma unroll
    for (int i = 0; i < 4; ++i)
      af[i] = *(const bf16x8_t*)(&As[cb * 4096 + abase + i * 512]);
#pragma unroll
    for (int j = 0; j < 4; ++j)
      bfg[j] = *(const bf16x8_t*)(&Bs[cb * 8192 + bbase + j * 512]);
#pragma unroll
    for (int i = 0; i < 4; ++i)
#pragma unroll
      for (int j = 0; j < 4; ++j)
        acc[i][j] = __builtin_amdgcn_mfma_f32_16x16x32_bf16(af[i], bfg[j], acc[i][j], 0, 0, 0);
  }
#undef STAGEG

  const int h = blockIdx.x * 4 + (w & 3);       // head 0..15 (one per wave)
  const int b = (m0 + wm) >> 11;                // batch

  if (z == 2) {
#pragma unroll
    for (int i = 0; i < 4; ++i) {
      const int sq = ((m0 + wm) & 2047) + i * 16 + qd * 4;
      const int pos = (sq & ~31) + 8 * qd + 4 * (i & 1);
#pragma unroll
      for (int j = 0; j < 4; ++j) {
        const int dk = j * 16 + l16;
        bf16x4_t ov;
#pragma unroll
        for (int r = 0; r < 4; ++r) ov[r] = (bf16)acc[i][j][r];
        *(bf16x4_t*)(Vt + ((size_t)((b * 16 + h) * 64 + dk)) * 2048 + pos) = ov;
      }
    }
    return;
  }

  const float* nw = (z == 0) ? qnw : knw;
  const float osc = (z == 0) ? 0.125f * 1.44269504088896f : 1.0f;
  bf16* Out = (z == 0) ? Qp : Kp;

  float nwv[4];
#pragma unroll
  for (int j = 0; j < 4; ++j) nwv[j] = nw[j * 16 + l16];
  float invf[2];
#pragma unroll
  for (int jj = 0; jj < 2; ++jj) {
    const int d = jj * 16 + l16;
    invf[jj] = __builtin_amdgcn_exp2f(-(float)(2 * d) * (18.93156857f / 64.0f)) * 0.15915494309f;
  }

  __syncthreads();                      // all waves done reading GEMM LDS
  bf16* ep = smem + w * 1152;           // 16 x 72 bf16 wave-private patch

#pragma unroll
  for (int i = 0; i < 4; ++i) {
    const int sbase = ((m0 + wm) & 2047) + i * 16 + qd * 4;
    float ssq[4];
#pragma unroll
    for (int r = 0; r < 4; ++r) {
      ssq[r] = 0.f;
#pragma unroll
      for (int j = 0; j < 4; ++j) ssq[r] += acc[i][j][r] * acc[i][j][r];
    }
#pragma unroll
    for (int off = 1; off < 16; off <<= 1)
#pragma unroll
      for (int r = 0; r < 4; ++r) ssq[r] += __shfl_xor(ssq[r], off);

    float xn[4][4];
#pragma unroll
    for (int r = 0; r < 4; ++r) {
      const float inv = 1.0f / sqrtf(ssq[r] * (1.0f / 64.0f) + 1e-10f);
#pragma unroll
      for (int j = 0; j < 4; ++j) xn[j][r] = acc[i][j][r] * inv * nwv[j];
    }
#pragma unroll
    for (int jj = 0; jj < 2; ++jj) {
#pragma unroll
      for (int r = 0; r < 4; ++r) {
        const int s = sbase + r;
        float rev = (float)s * invf[jj];
        rev = rev - floorf(rev);
        const float cv = __builtin_amdgcn_cosf(rev);
        const float sv = __builtin_amdgcn_sinf(rev);
        const float o1 = (xn[jj][r] * cv - xn[jj + 2][r] * sv) * osc;
        const float o2 = (xn[jj + 2][r] * cv + xn[jj][r] * sv) * osc;
        const int prow = qd * 4 + r;
        ep[prow * 72 + jj * 16 + l16] = (bf16)o1;
        ep[prow * 72 + 32 + jj * 16 + l16] = (bf16)o2;
      }
    }
    const int sg = ((m0 + wm) & 2047) + i * 16 + l16;
    const bf16x8_t t0 = *(const bf16x8_t*)(ep + l16 * 72 + qd * 16);
    const bf16x8_t t1 = *(const bf16x8_t*)(ep + l16 * 72 + qd * 16 + 8);
    bf16* gb = Out + ((size_t)(b * 16 + h) * 2048 + sg) * 64 + qd * 16;
    *(bf16x8_t*)(gb) = t0;
    *(bf16x8_t*)(gb + 8) = t1;
  }
}

// ---------------------------------------------------------------------------
// Output projection GEMM; fp32 out via LDS-transposed f32x4 stores.
// R9 chunked swizzle kept. (R7-exact)
// ---------------------------------------------------------------------------
__global__ __launch_bounds__(256) void gemm_out_k(
    const bf16* __restrict__ Ob, const bf16* __restrict__ wob, float* __restrict__ out)
{
  __shared__ bf16 smem[24576];
  const int N = 1024;

  const int orig = blockIdx.x + 8 * blockIdx.y;
  const int wgid = (orig & 7) * 32 + (orig >> 3);
  const int by = wgid >> 3, bx = wgid & 7;

  const int m0 = by * 128, n0 = bx * 128;
  f32x4_t acc[4][4] = {};
  gemm_core(Ob, wob, m0, n0, smem, acc);

  const int t = threadIdx.x;
  const int lane = t & 63, w = t >> 6;
  const int l16 = lane & 15, qd = lane >> 4;
  const int wm = (w & 1) * 64, wn = (w >> 1) * 64;

  __syncthreads();
  float* epf = (float*)smem + w * 1088;   // 16 x 68 f32 wave-private patch

#pragma unroll
  for (int i = 0; i < 4; ++i) {
#pragma unroll
    for (int j = 0; j < 4; ++j)
#pragma unroll
      for (int r = 0; r < 4; ++r)
        epf[(qd * 4 + r) * 68 + j * 16 + l16] = acc[i][j][r];
    const int row = m0 + wm + i * 16 + l16;
#pragma unroll
    for (int c = 0; c < 4; ++c) {
      const f32x4_t vv = *(const f32x4_t*)(epf + l16 * 68 + qd * 16 + c * 4);
      *(f32x4_t*)(out + (size_t)row * N + n0 + wn + qd * 16 + c * 4) = vv;
    }
  }
}

// ---------------------------------------------------------------------------
// Causal flash attention — KVBLK=64, T1 chunked swizzle, R17 complementary-qt
// CU pairing, T5 setprio. (R10-exact champion version)
// ---------------------------------------------------------------------------
__global__ __launch_bounds__(512) void flash_attn(
    const bf16* __restrict__ Qp, const bf16* __restrict__ Kp,
    const bf16* __restrict__ Vt, bf16* __restrict__ O)
{
  const int S = 2048;

  const int orig = blockIdx.x + 16 * blockIdx.y;
  const int wgid = (orig & 7) * 64 + (orig >> 3);
  const int u = wgid & 63;
  const int bh = wgid >> 4;                    // 4 bh per XCD chunk
  const int x = u & 15;
  const int qt = (u < 32) ? (15 - x) : x;      // complementary pairing

  const int t = threadIdx.x;
  const int lane = t & 63, w = t >> 6;
  const int l16 = lane & 15, qd = lane >> 4;

  __shared__ bf16 Ks[3][64 * 64];
  __shared__ bf16 Vs[3][64 * 64];

  const int qrow = qt * 128 + w * 16 + l16;
  const bf16* qbase = Qp + ((size_t)bh * S + qrow) * 64 + qd * 8;
  const bf16x8_t qf0 = *(const bf16x8_t*)qbase;
  const bf16x8_t qf1 = *(const bf16x8_t*)(qbase + 32);

  f32x4_t o_acc[4] = {};
  float l_i = 0.f;

  const int srow = t >> 3;
  const int scol = ((t & 7) ^ (srow & 7)) * 8;
  const bf16* kg = Kp + ((size_t)bh * S + srow) * 64 + scol;
  const bf16* vg = Vt + ((size_t)(bh * 64 + srow)) * S + scol;
  const int lo = w * 512;

  const int sw = l16 & 7;

#define STAGE(kt_, b_)                                 \
  do {                                                 \
    GLD_LDS16(kg + (size_t)(kt_) * 4096, &Ks[b_][lo]); \
    GLD_LDS16(vg + (kt_) * 64, &Vs[b_][lo]);           \
  } while (0)

  const int ktmax = 2 * qt + 1;
  STAGE(0, 0);
  STAGE(1, 1);

  for (int kt = 0; kt <= ktmax; ++kt) {
    const int cb = kt - (kt / 3) * 3;
    if (kt < ktmax) S_WAITCNT_VMCNT(2); else S_WAITCNT_VMCNT(0);
    S_BARRIER();
    if (kt + 2 <= ktmax) {
      const int nb = (kt + 2) - ((kt + 2) / 3) * 3;
      STAGE(kt + 2, nb);
    }

    if (kt == ktmax && w < 4) continue;

    f32x4_t sf[4];
    __builtin_amdgcn_s_setprio(1);
#pragma unroll
    for (int nt = 0; nt < 4; ++nt) {
      sf[nt][0] = -12.f; sf[nt][1] = -12.f; sf[nt][2] = -12.f; sf[nt][3] = -12.f;
      const bf16x8_t kf0 = *(const bf16x8_t*)(&Ks[cb][(nt * 16 + l16) * 64 + ((0 + qd) ^ sw) * 8]);
      const bf16x8_t kf1 = *(const bf16x8_t*)(&Ks[cb][(nt * 16 + l16) * 64 + ((4 + qd) ^ sw) * 8]);
      sf[nt] = __builtin_amdgcn_mfma_f32_16x16x32_bf16(kf0, qf0, sf[nt], 0, 0, 0);
      sf[nt] = __builtin_amdgcn_mfma_f32_16x16x32_bf16(kf1, qf1, sf[nt], 0, 0, 0);
    }
    __builtin_amdgcn_s_setprio(0);

    if (kt >= ktmax - 1) {
      const int kofs = (kt - 2 * qt) * 64;
      const int q_local = w * 16 + l16;
#pragma unroll
      for (int nt = 0; nt < 4; ++nt)
#pragma unroll
        for (int r = 0; r < 4; ++r)
          if (kofs + nt * 16 + qd * 4 + r > q_local) sf[nt][r] = -100.f;
    }

    bf16x4_t pb[4];
#pragma unroll
    for (int nt = 0; nt < 4; ++nt)
#pragma unroll
      for (int r = 0; r < 4; ++r) {
        const float p = __builtin_amdgcn_exp2f(sf[nt][r]);
        l_i += p;
        pb[nt][r] = (bf16)p;
      }

    __builtin_amdgcn_s_setprio(1);
#pragma unroll
    for (int nt2 = 0; nt2 < 2; ++nt2) {
      bf16x8_t pf;
#pragma unroll
      for (int r = 0; r < 4; ++r) { pf[r] = pb[2 * nt2][r]; pf[4 + r] = pb[2 * nt2 + 1][r]; }
#pragma unroll
      for (int dt = 0; dt < 4; ++dt) {
        const int row = dt * 16 + l16;
        const bf16x8_t vf =
            *(const bf16x8_t*)(&Vs[cb][row * 64 + ((4 * nt2 + qd) ^ sw) * 8]);
        o_acc[dt] = __builtin_amdgcn_mfma_f32_16x16x32_bf16(vf, pf, o_acc[dt], 0, 0, 0);
      }
    }
    __builtin_amdgcn_s_setprio(0);
  }
#undef STAGE

  l_i += __shfl_xor(l_i, 16);
  l_i += __shfl_xor(l_i, 32);

  const int b = bh >> 4, h = bh & 15;
  const float inv_l = 1.0f / l_i;
  const int qg = qt * 128 + w * 16 + l16;
#pragma unroll
  for (int dt = 0; dt < 4; ++dt) {
    bf16x4_t ov;
#pragma unroll
    for (int r = 0; r < 4; ++r) ov[r] = (bf16)(o_acc[dt][r] * inv_l);
    *(bf16x4_t*)(O + ((size_t)(b * S + qg)) * 1024 + h * 64 + dt * 16 + qd * 4) = ov;
  }
}

// ---------------------------------------------------------------------------
extern "C" void kernel_launch(void* const* d_in, const int* in_sizes, int n_in,
                              void* d_out, int out_size, void* d_ws, size_t ws_size,
                              hipStream_t stream)
{
  const float* q   = (const float*)d_in[0];
  const float* k   = (const float*)d_in[1];
  const float* v   = (const float*)d_in[2];
  const float* wq  = (const float*)d_in[3];
  const float* wk  = (const float*)d_in[4];
  const float* wv  = (const float*)d_in[5];
  const float* wo  = (const float*)d_in[6];
  const float* qnw = (const float*)d_in[7];
  const float* knw = (const float*)d_in[8];

  char* ws = (char*)d_ws;
  const size_t MB = 1u << 20;
  bf16* qb  = (bf16*)(ws + 0 * MB);    // dead after gemm_qkv
  bf16* kb  = (bf16*)(ws + 8 * MB);
  bf16* vb  = (bf16*)(ws + 16 * MB);
  bf16* wqb = (bf16*)(ws + 24 * MB);
  bf16* wkb = (bf16*)(ws + 26 * MB);
  bf16* wvb = (bf16*)(ws + 28 * MB);
  bf16* wob = (bf16*)(ws + 30 * MB);
  bf16* Qp  = (bf16*)(ws + 32 * MB);
  bf16* Kp  = (bf16*)(ws + 40 * MB);
  bf16* Vtr = (bf16*)(ws + 48 * MB);
  bf16* Oattn = qb;                    // alias: qb dead once flash starts

  cvt_kernel<<<dim3(1024, 7), 256, 0, stream>>>(q, k, v, wq, wk, wv, wo,
                                                qb, kb, vb, wqb, wkb, wvb, wob);
  gemm_qkv<<<dim3(4, 32, 3), 512, 0, stream>>>(qb, wqb, kb, wkb, vb, wvb,
                                               qnw, knw, Qp, Kp, Vtr);
  flash_attn<<<dim3(16, 32), 512, 0, stream>>>(Qp, Kp, Vtr, Oattn);
  gemm_out_k<<<dim3(8, 32), 256, 0, stream>>>(Oattn, wob, (float*)d_out);
}

// Round 12
// 203.272 us; speedup vs baseline: 1.0162x; 1.0162x over previous
//
#include <hip/hip_runtime.h>
#include <cstdint>
#include <cstddef>

typedef __bf16 bf16;
typedef __bf16 bf16x4_t __attribute__((ext_vector_type(4)));
typedef __bf16 bf16x8_t __attribute__((ext_vector_type(8)));
typedef float  f32x4_t  __attribute__((ext_vector_type(4)));

#define GLD_LDS16(g, l)                                                              \
  __builtin_amdgcn_global_load_lds((const __attribute__((address_space(1))) void*)(g), \
                                   (__attribute__((address_space(3))) void*)(l), 16, 0, 0)

#define S_WAITCNT_VMCNT(N) asm volatile("s_waitcnt vmcnt(" #N ")" ::: "memory")
#define S_BARRIER() asm volatile("s_barrier" ::: "memory")

// ---------------------------------------------------------------------------
// fp32 -> bf16 conversion, grid-stride, 16B stores (R18; at HBM roofline).
// ---------------------------------------------------------------------------
__global__ __launch_bounds__(256) void cvt_kernel(
    const float* __restrict__ q, const float* __restrict__ k, const float* __restrict__ v,
    const float* __restrict__ wq, const float* __restrict__ wk, const float* __restrict__ wv,
    const float* __restrict__ wo,
    bf16* __restrict__ qb, bf16* __restrict__ kb, bf16* __restrict__ vb,
    bf16* __restrict__ wqb, bf16* __restrict__ wkb, bf16* __restrict__ wvb,
    bf16* __restrict__ wob)
{
  const float* src; bf16* dst; int n;
  switch (blockIdx.y) {
    case 0: src = q;  dst = qb;  n = 4194304; break;
    case 1: src = k;  dst = kb;  n = 4194304; break;
    case 2: src = v;  dst = vb;  n = 4194304; break;
    case 3: src = wq; dst = wqb; n = 1048576; break;
    case 4: src = wk; dst = wkb; n = 1048576; break;
    case 5: src = wv; dst = wvb; n = 1048576; break;
    default: src = wo; dst = wob; n = 1048576; break;
  }
  const int nv8 = n >> 3;                      // 8-float chunks
  const int stride = gridDim.x * 256;
  const float4* s4 = (const float4*)src;
  bf16x8_t* d8 = (bf16x8_t*)dst;
  for (int i = blockIdx.x * 256 + threadIdx.x; i < nv8; i += stride) {
    const float4 f0 = s4[2 * i];
    const float4 f1 = s4[2 * i + 1];
    bf16x8_t o;
    o[0] = (bf16)f0.x; o[1] = (bf16)f0.y; o[2] = (bf16)f0.z; o[3] = (bf16)f0.w;
    o[4] = (bf16)f1.x; o[5] = (bf16)f1.y; o[6] = (bf16)f1.z; o[7] = (bf16)f1.w;
    d8[i] = o;
  }
}

// ---------------------------------------------------------------------------
// 128x128 GEMM main loop (B^T weights), used by gemm_out_k. Triple-buffered
// LDS, prefetch distance 2, vmcnt(4)+raw-barrier pipeline. SLOT8 swizzle.
// ---------------------------------------------------------------------------
__device__ __forceinline__ void gemm_core(const bf16* __restrict__ A,
                                          const bf16* __restrict__ W,
                                          int m0, int n0, bf16* smem,
                                          f32x4_t (&acc)[4][4])
{
  const int K = 1024;
  bf16* As = smem;
  bf16* Bs = smem + 12288;
  const int t = threadIdx.x;
  const int lane = t & 63, w = t >> 6;
  const int l16 = lane & 15, qd = lane >> 4;
  const int wm = (w & 1) * 64, wn = (w >> 1) * 64;

  const int p8 = t >> 3;
  const int vslot = (t & 7) ^ (p8 & 7);
  const int srow = 2 * p8 + (vslot >> 2);
  const int scc = vslot & 3;
  const bf16* ag0 = A + (size_t)(m0 + srow) * K + scc * 8;
  const bf16* ag1 = A + (size_t)(m0 + 64 + srow) * K + scc * 8;
  const bf16* wg0 = W + (size_t)(n0 + srow) * K + scc * 8;
  const bf16* wg1 = W + (size_t)(n0 + 64 + srow) * K + scc * 8;
  const int lo0 = (w * 64) * 8;
  const int lo1 = (256 + w * 64) * 8;

  const int rslot = (((l16 & 1) * 4 + qd) ^ ((l16 >> 1) & 7)) * 8;
  const int abase = (wm >> 6) * 2048 + (l16 >> 1) * 64 + rslot;
  const int bbase = (wn >> 6) * 2048 + (l16 >> 1) * 64 + rslot;

#define STAGEG(k0_, b_)                                  \
  do {                                                   \
    GLD_LDS16(ag0 + (k0_), &As[(b_) * 4096 + lo0]);      \
    GLD_LDS16(ag1 + (k0_), &As[(b_) * 4096 + lo1]);      \
    GLD_LDS16(wg0 + (k0_), &Bs[(b_) * 4096 + lo0]);      \
    GLD_LDS16(wg1 + (k0_), &Bs[(b_) * 4096 + lo1]);      \
  } while (0)

  STAGEG(0, 0);
  STAGEG(32, 1);

  for (int k0 = 0; k0 < K; k0 += 32) {
    const int it = k0 >> 5;
    const int cb = it - (it / 3) * 3;
    if (k0 + 32 < K) S_WAITCNT_VMCNT(4); else S_WAITCNT_VMCNT(0);
    S_BARRIER();
    if (k0 + 64 < K) {
      const int nb = (it + 2) - ((it + 2) / 3) * 3;
      STAGEG(k0 + 64, nb);
    }
    bf16x8_t af[4], bfg[4];
#pragma unroll
    for (int i = 0; i < 4; ++i)
      af[i] = *(const bf16x8_t*)(&As[cb * 4096 + abase + i * 512]);
#pragma unroll
    for (int j = 0; j < 4; ++j)
      bfg[j] = *(const bf16x8_t*)(&Bs[cb * 4096 + bbase + j * 512]);
#pragma unroll
    for (int i = 0; i < 4; ++i)
#pragma unroll
      for (int j = 0; j < 4; ++j)
        acc[i][j] = __builtin_amdgcn_mfma_f32_16x16x32_bf16(af[i], bfg[j], acc[i][j], 0, 0, 0);
  }
#undef STAGEG
}

// ---------------------------------------------------------------------------
// Fused QKV projection, 128x256 tile (R19: 100% fill, 2 WG/CU, 72KB LDS).
// Kept — R11 showed qkv dropped below the 41us fill kernels (from 44.1);
// the +1.7us total delta is inside the observed cross-run noise band.
// ---------------------------------------------------------------------------
__global__ __launch_bounds__(512) void gemm_qkv(
    const bf16* __restrict__ qb, const bf16* __restrict__ wqb,
    const bf16* __restrict__ kb, const bf16* __restrict__ wkb,
    const bf16* __restrict__ vb, const bf16* __restrict__ wvb,
    const float* __restrict__ qnw, const float* __restrict__ knw,
    bf16* __restrict__ Qp, bf16* __restrict__ Kp, bf16* __restrict__ Vt)
{
  __shared__ bf16 smem[36864];
  const int K = 1024;
  const int z = blockIdx.z;
  const bf16 *A, *W;
  if (z == 0)      { A = qb; W = wqb; }
  else if (z == 1) { A = kb; W = wkb; }
  else             { A = vb; W = wvb; }

  const int m0 = blockIdx.y * 128, n0 = blockIdx.x * 256;
  const int t = threadIdx.x;
  const int lane = t & 63, w = t >> 6;
  const int l16 = lane & 15, qd = lane >> 4;
  const int wm = ((w >> 2) & 1) * 64, wn = (w & 3) * 64;

  bf16* As = smem;                 // 3 buffers x 4096 (128 rows x 32 k)
  bf16* Bs = smem + 12288;         // 3 buffers x 8192 (256 rows x 32 k)

  const int p8 = t >> 3;                 // row pair 0..63
  const int vslot = (t & 7) ^ (p8 & 7);
  const int srow = 2 * p8 + (vslot >> 2);
  const int scc = vslot & 3;
  const bf16* ag0 = A + (size_t)(m0 + srow) * K + scc * 8;        // A: 128 rows
  const bf16* wg0 = W + (size_t)(n0 + srow) * K + scc * 8;        // B half 0
  const bf16* wg1 = W + (size_t)(n0 + 128 + srow) * K + scc * 8;  // B half 1
  const int lo0 = t * 8;
  const int lo1 = 4096 + t * 8;

  const int rslot = (((l16 & 1) * 4 + qd) ^ ((l16 >> 1) & 7)) * 8;
  const int abase = (((w >> 2) & 1) * 32 + (l16 >> 1)) * 64 + rslot;
  const int bbase = ((w >> 1) & 1) * 4096 + ((w & 1) * 32 + (l16 >> 1)) * 64 + rslot;

  f32x4_t acc[4][4] = {};

#define STAGEG(k0_, b_)                                  \
  do {                                                   \
    GLD_LDS16(ag0 + (k0_), &As[(b_) * 4096 + lo0]);      \
    GLD_LDS16(wg0 + (k0_), &Bs[(b_) * 8192 + lo0]);      \
    GLD_LDS16(wg1 + (k0_), &Bs[(b_) * 8192 + lo1]);      \
  } while (0)

  STAGEG(0, 0);
  STAGEG(32, 1);

  for (int kk = 0; kk < 32; ++kk) {
    const int cb = kk - (kk / 3) * 3;           // kk % 3
    if (kk < 31) S_WAITCNT_VMCNT(3); else S_WAITCNT_VMCNT(0);
    S_BARRIER();
    if (kk + 2 < 32) {
      const int nb = (kk + 2) - ((kk + 2) / 3) * 3;
      STAGEG((kk + 2) * 32, nb);
    }
    bf16x8_t af[4], bfg[4];
#pragma unroll
    for (int i = 0; i < 4; ++i)
      af[i] = *(const bf16x8_t*)(&As[cb * 4096 + abase + i * 512]);
#pragma unroll
    for (int j = 0; j < 4; ++j)
      bfg[j] = *(const bf16x8_t*)(&Bs[cb * 8192 + bbase + j * 512]);
#pragma unroll
    for (int i = 0; i < 4; ++i)
#pragma unroll
      for (int j = 0; j < 4; ++j)
        acc[i][j] = __builtin_amdgcn_mfma_f32_16x16x32_bf16(af[i], bfg[j], acc[i][j], 0, 0, 0);
  }
#undef STAGEG

  const int h = blockIdx.x * 4 + (w & 3);       // head 0..15 (one per wave)
  const int b = (m0 + wm) >> 11;                // batch

  if (z == 2) {
#pragma unroll
    for (int i = 0; i < 4; ++i) {
      const int sq = ((m0 + wm) & 2047) + i * 16 + qd * 4;
      const int pos = (sq & ~31) + 8 * qd + 4 * (i & 1);
#pragma unroll
      for (int j = 0; j < 4; ++j) {
        const int dk = j * 16 + l16;
        bf16x4_t ov;
#pragma unroll
        for (int r = 0; r < 4; ++r) ov[r] = (bf16)acc[i][j][r];
        *(bf16x4_t*)(Vt + ((size_t)((b * 16 + h) * 64 + dk)) * 2048 + pos) = ov;
      }
    }
    return;
  }

  const float* nw = (z == 0) ? qnw : knw;
  const float osc = (z == 0) ? 0.125f * 1.44269504088896f : 1.0f;
  bf16* Out = (z == 0) ? Qp : Kp;

  float nwv[4];
#pragma unroll
  for (int j = 0; j < 4; ++j) nwv[j] = nw[j * 16 + l16];
  float invf[2];
#pragma unroll
  for (int jj = 0; jj < 2; ++jj) {
    const int d = jj * 16 + l16;
    invf[jj] = __builtin_amdgcn_exp2f(-(float)(2 * d) * (18.93156857f / 64.0f)) * 0.15915494309f;
  }

  __syncthreads();                      // all waves done reading GEMM LDS
  bf16* ep = smem + w * 1152;           // 16 x 72 bf16 wave-private patch

#pragma unroll
  for (int i = 0; i < 4; ++i) {
    const int sbase = ((m0 + wm) & 2047) + i * 16 + qd * 4;
    float ssq[4];
#pragma unroll
    for (int r = 0; r < 4; ++r) {
      ssq[r] = 0.f;
#pragma unroll
      for (int j = 0; j < 4; ++j) ssq[r] += acc[i][j][r] * acc[i][j][r];
    }
#pragma unroll
    for (int off = 1; off < 16; off <<= 1)
#pragma unroll
      for (int r = 0; r < 4; ++r) ssq[r] += __shfl_xor(ssq[r], off);

    float xn[4][4];
#pragma unroll
    for (int r = 0; r < 4; ++r) {
      const float inv = 1.0f / sqrtf(ssq[r] * (1.0f / 64.0f) + 1e-10f);
#pragma unroll
      for (int j = 0; j < 4; ++j) xn[j][r] = acc[i][j][r] * inv * nwv[j];
    }
#pragma unroll
    for (int jj = 0; jj < 2; ++jj) {
#pragma unroll
      for (int r = 0; r < 4; ++r) {
        const int s = sbase + r;
        float rev = (float)s * invf[jj];
        rev = rev - floorf(rev);
        const float cv = __builtin_amdgcn_cosf(rev);
        const float sv = __builtin_amdgcn_sinf(rev);
        const float o1 = (xn[jj][r] * cv - xn[jj + 2][r] * sv) * osc;
        const float o2 = (xn[jj + 2][r] * cv + xn[jj][r] * sv) * osc;
        const int prow = qd * 4 + r;
        ep[prow * 72 + jj * 16 + l16] = (bf16)o1;
        ep[prow * 72 + 32 + jj * 16 + l16] = (bf16)o2;
      }
    }
    const int sg = ((m0 + wm) & 2047) + i * 16 + l16;
    const bf16x8_t t0 = *(const bf16x8_t*)(ep + l16 * 72 + qd * 16);
    const bf16x8_t t1 = *(const bf16x8_t*)(ep + l16 * 72 + qd * 16 + 8);
    bf16* gb = Out + ((size_t)(b * 16 + h) * 2048 + sg) * 64 + qd * 16;
    *(bf16x8_t*)(gb) = t0;
    *(bf16x8_t*)(gb + 8) = t1;
  }
}

// ---------------------------------------------------------------------------
// Output projection GEMM; fp32 out via LDS-transposed f32x4 stores.
// R9 chunked swizzle kept. (R7-exact)
// ---------------------------------------------------------------------------
__global__ __launch_bounds__(256) void gemm_out_k(
    const bf16* __restrict__ Ob, const bf16* __restrict__ wob, float* __restrict__ out)
{
  __shared__ bf16 smem[24576];
  const int N = 1024;

  const int orig = blockIdx.x + 8 * blockIdx.y;
  const int wgid = (orig & 7) * 32 + (orig >> 3);
  const int by = wgid >> 3, bx = wgid & 7;

  const int m0 = by * 128, n0 = bx * 128;
  f32x4_t acc[4][4] = {};
  gemm_core(Ob, wob, m0, n0, smem, acc);

  const int t = threadIdx.x;
  const int lane = t & 63, w = t >> 6;
  const int l16 = lane & 15, qd = lane >> 4;
  const int wm = (w & 1) * 64, wn = (w >> 1) * 64;

  __syncthreads();
  float* epf = (float*)smem + w * 1088;   // 16 x 68 f32 wave-private patch

#pragma unroll
  for (int i = 0; i < 4; ++i) {
#pragma unroll
    for (int j = 0; j < 4; ++j)
#pragma unroll
      for (int r = 0; r < 4; ++r)
        epf[(qd * 4 + r) * 68 + j * 16 + l16] = acc[i][j][r];
    const int row = m0 + wm + i * 16 + l16;
#pragma unroll
    for (int c = 0; c < 4; ++c) {
      const f32x4_t vv = *(const f32x4_t*)(epf + l16 * 68 + qd * 16 + c * 4);
      *(f32x4_t*)(out + (size_t)row * N + n0 + wn + qd * 16 + c * 4) = vv;
    }
  }
}

// ---------------------------------------------------------------------------
// Causal flash attention — KVBLK=64, T1 chunked swizzle, R17 complementary-qt
// CU pairing, T5 setprio. R20: prefetch deepened to 4 buffers / distance-3
// (64KB LDS; 2 WG/CU preserved: 128KB/CU LDS, VGPR 88 -> 5 waves/SIMD cap).
// Ledger: outstanding stages at iter kt = [kt, min(kt+2,ktmax)] -> wait
// vmcnt(4)/(2)/(0) for 3/2/1 stages; refill of buffer (kt+3)&3 is issued
// after the kt barrier, and that buffer's previous tile (kt-1) was consumed
// in iteration kt-1 by all waves (they arrived at this barrier) -> no race.
// ---------------------------------------------------------------------------
__global__ __launch_bounds__(512) void flash_attn(
    const bf16* __restrict__ Qp, const bf16* __restrict__ Kp,
    const bf16* __restrict__ Vt, bf16* __restrict__ O)
{
  const int S = 2048;

  const int orig = blockIdx.x + 16 * blockIdx.y;
  const int wgid = (orig & 7) * 64 + (orig >> 3);
  const int u = wgid & 63;
  const int bh = wgid >> 4;                    // 4 bh per XCD chunk
  const int x = u & 15;
  const int qt = (u < 32) ? (15 - x) : x;      // complementary pairing

  const int t = threadIdx.x;
  const int lane = t & 63, w = t >> 6;
  const int l16 = lane & 15, qd = lane >> 4;

  __shared__ bf16 Ks[4][64 * 64];
  __shared__ bf16 Vs[4][64 * 64];

  const int qrow = qt * 128 + w * 16 + l16;
  const bf16* qbase = Qp + ((size_t)bh * S + qrow) * 64 + qd * 8;
  const bf16x8_t qf0 = *(const bf16x8_t*)qbase;
  const bf16x8_t qf1 = *(const bf16x8_t*)(qbase + 32);

  f32x4_t o_acc[4] = {};
  float l_i = 0.f;

  const int srow = t >> 3;
  const int scol = ((t & 7) ^ (srow & 7)) * 8;
  const bf16* kg = Kp + ((size_t)bh * S + srow) * 64 + scol;
  const bf16* vg = Vt + ((size_t)(bh * 64 + srow)) * S + scol;
  const int lo = w * 512;

  const int sw = l16 & 7;

#define STAGE(kt_, b_)                                 \
  do {                                                 \
    GLD_LDS16(kg + (size_t)(kt_) * 4096, &Ks[b_][lo]); \
    GLD_LDS16(vg + (kt_) * 64, &Vs[b_][lo]);           \
  } while (0)

  const int ktmax = 2 * qt + 1;                // >= 1 always
  STAGE(0, 0);
  STAGE(1, 1);
  if (ktmax >= 2) STAGE(2, 2);

  for (int kt = 0; kt <= ktmax; ++kt) {
    const int cb = kt & 3;
    if (kt + 2 <= ktmax)      S_WAITCNT_VMCNT(4);
    else if (kt < ktmax)      S_WAITCNT_VMCNT(2);
    else                      S_WAITCNT_VMCNT(0);
    S_BARRIER();
    if (kt + 3 <= ktmax) {
      STAGE(kt + 3, (kt + 3) & 3);
    }

    if (kt == ktmax && w < 4) continue;

    f32x4_t sf[4];
    __builtin_amdgcn_s_setprio(1);
#pragma unroll
    for (int nt = 0; nt < 4; ++nt) {
      sf[nt][0] = -12.f; sf[nt][1] = -12.f; sf[nt][2] = -12.f; sf[nt][3] = -12.f;
      const bf16x8_t kf0 = *(const bf16x8_t*)(&Ks[cb][(nt * 16 + l16) * 64 + ((0 + qd) ^ sw) * 8]);
      const bf16x8_t kf1 = *(const bf16x8_t*)(&Ks[cb][(nt * 16 + l16) * 64 + ((4 + qd) ^ sw) * 8]);
      sf[nt] = __builtin_amdgcn_mfma_f32_16x16x32_bf16(kf0, qf0, sf[nt], 0, 0, 0);
      sf[nt] = __builtin_amdgcn_mfma_f32_16x16x32_bf16(kf1, qf1, sf[nt], 0, 0, 0);
    }
    __builtin_amdgcn_s_setprio(0);

    if (kt >= ktmax - 1) {
      const int kofs = (kt - 2 * qt) * 64;
      const int q_local = w * 16 + l16;
#pragma unroll
      for (int nt = 0; nt < 4; ++nt)
#pragma unroll
        for (int r = 0; r < 4; ++r)
          if (kofs + nt * 16 + qd * 4 + r > q_local) sf[nt][r] = -100.f;
    }

    bf16x4_t pb[4];
#pragma unroll
    for (int nt = 0; nt < 4; ++nt)
#pragma unroll
      for (int r = 0; r < 4; ++r) {
        const float p = __builtin_amdgcn_exp2f(sf[nt][r]);
        l_i += p;
        pb[nt][r] = (bf16)p;
      }

    __builtin_amdgcn_s_setprio(1);
#pragma unroll
    for (int nt2 = 0; nt2 < 2; ++nt2) {
      bf16x8_t pf;
#pragma unroll
      for (int r = 0; r < 4; ++r) { pf[r] = pb[2 * nt2][r]; pf[4 + r] = pb[2 * nt2 + 1][r]; }
#pragma unroll
      for (int dt = 0; dt < 4; ++dt) {
        const int row = dt * 16 + l16;
        const bf16x8_t vf =
            *(const bf16x8_t*)(&Vs[cb][row * 64 + ((4 * nt2 + qd) ^ sw) * 8]);
        o_acc[dt] = __builtin_amdgcn_mfma_f32_16x16x32_bf16(vf, pf, o_acc[dt], 0, 0, 0);
      }
    }
    __builtin_amdgcn_s_setprio(0);
  }
#undef STAGE

  l_i += __shfl_xor(l_i, 16);
  l_i += __shfl_xor(l_i, 32);

  const int b = bh >> 4, h = bh & 15;
  const float inv_l = 1.0f / l_i;
  const int qg = qt * 128 + w * 16 + l16;
#pragma unroll
  for (int dt = 0; dt < 4; ++dt) {
    bf16x4_t ov;
#pragma unroll
    for (int r = 0; r < 4; ++r) ov[r] = (bf16)(o_acc[dt][r] * inv_l);
    *(bf16x4_t*)(O + ((size_t)(b * S + qg)) * 1024 + h * 64 + dt * 16 + qd * 4) = ov;
  }
}

// ---------------------------------------------------------------------------
extern "C" void kernel_launch(void* const* d_in, const int* in_sizes, int n_in,
                              void* d_out, int out_size, void* d_ws, size_t ws_size,
                              hipStream_t stream)
{
  const float* q   = (const float*)d_in[0];
  const float* k   = (const float*)d_in[1];
  const float* v   = (const float*)d_in[2];
  const float* wq  = (const float*)d_in[3];
  const float* wk  = (const float*)d_in[4];
  const float* wv  = (const float*)d_in[5];
  const float* wo  = (const float*)d_in[6];
  const float* qnw = (const float*)d_in[7];
  const float* knw = (const float*)d_in[8];

  char* ws = (char*)d_ws;
  const size_t MB = 1u << 20;
  bf16* qb  = (bf16*)(ws + 0 * MB);    // dead after gemm_qkv
  bf16* kb  = (bf16*)(ws + 8 * MB);
  bf16* vb  = (bf16*)(ws + 16 * MB);
  bf16* wqb = (bf16*)(ws + 24 * MB);
  bf16* wkb = (bf16*)(ws + 26 * MB);
  bf16* wvb = (bf16*)(ws + 28 * MB);
  bf16* wob = (bf16*)(ws + 30 * MB);
  bf16* Qp  = (bf16*)(ws + 32 * MB);
  bf16* Kp  = (bf16*)(ws + 40 * MB);
  bf16* Vtr = (bf16*)(ws + 48 * MB);
  bf16* Oattn = qb;                    // alias: qb dead once flash starts

  cvt_kernel<<<dim3(1024, 7), 256, 0, stream>>>(q, k, v, wq, wk, wv, wo,
                                                qb, kb, vb, wqb, wkb, wvb, wob);
  gemm_qkv<<<dim3(4, 32, 3), 512, 0, stream>>>(qb, wqb, kb, wkb, vb, wvb,
                                               qnw, knw, Qp, Kp, Vtr);
  flash_attn<<<dim3(16, 32), 512, 0, stream>>>(Qp, Kp, Vtr, Oattn);
  gemm_out_k<<<dim3(8, 32), 256, 0, stream>>>(Oattn, wob, (float*)d_out);
}

// Round 13
// 197.591 us; speedup vs baseline: 1.0455x; 1.0288x over previous
//
#include <hip/hip_runtime.h>
#include <cstdint>
#include <cstddef>

typedef __bf16 bf16;
typedef __bf16 bf16x4_t __attribute__((ext_vector_type(4)));
typedef __bf16 bf16x8_t __attribute__((ext_vector_type(8)));
typedef float  f32x4_t  __attribute__((ext_vector_type(4)));

#define GLD_LDS16(g, l)                                                              \
  __builtin_amdgcn_global_load_lds((const __attribute__((address_space(1))) void*)(g), \
                                   (__attribute__((address_space(3))) void*)(l), 16, 0, 0)

#define S_WAITCNT_VMCNT(N) asm volatile("s_waitcnt vmcnt(" #N ")" ::: "memory")
#define S_BARRIER() asm volatile("s_barrier" ::: "memory")

// ---------------------------------------------------------------------------
// fp32 -> bf16 conversion, grid-stride, 16B stores (R18; at HBM roofline).
// ---------------------------------------------------------------------------
__global__ __launch_bounds__(256) void cvt_kernel(
    const float* __restrict__ q, const float* __restrict__ k, const float* __restrict__ v,
    const float* __restrict__ wq, const float* __restrict__ wk, const float* __restrict__ wv,
    const float* __restrict__ wo,
    bf16* __restrict__ qb, bf16* __restrict__ kb, bf16* __restrict__ vb,
    bf16* __restrict__ wqb, bf16* __restrict__ wkb, bf16* __restrict__ wvb,
    bf16* __restrict__ wob)
{
  const float* src; bf16* dst; int n;
  switch (blockIdx.y) {
    case 0: src = q;  dst = qb;  n = 4194304; break;
    case 1: src = k;  dst = kb;  n = 4194304; break;
    case 2: src = v;  dst = vb;  n = 4194304; break;
    case 3: src = wq; dst = wqb; n = 1048576; break;
    case 4: src = wk; dst = wkb; n = 1048576; break;
    case 5: src = wv; dst = wvb; n = 1048576; break;
    default: src = wo; dst = wob; n = 1048576; break;
  }
  const int nv8 = n >> 3;                      // 8-float chunks
  const int stride = gridDim.x * 256;
  const float4* s4 = (const float4*)src;
  bf16x8_t* d8 = (bf16x8_t*)dst;
  for (int i = blockIdx.x * 256 + threadIdx.x; i < nv8; i += stride) {
    const float4 f0 = s4[2 * i];
    const float4 f1 = s4[2 * i + 1];
    bf16x8_t o;
    o[0] = (bf16)f0.x; o[1] = (bf16)f0.y; o[2] = (bf16)f0.z; o[3] = (bf16)f0.w;
    o[4] = (bf16)f1.x; o[5] = (bf16)f1.y; o[6] = (bf16)f1.z; o[7] = (bf16)f1.w;
    d8[i] = o;
  }
}

// ---------------------------------------------------------------------------
// Fused QKV projection, 128x256 tile (R19: 100% fill, 2 WG/CU, 72KB LDS).
// ---------------------------------------------------------------------------
__global__ __launch_bounds__(512) void gemm_qkv(
    const bf16* __restrict__ qb, const bf16* __restrict__ wqb,
    const bf16* __restrict__ kb, const bf16* __restrict__ wkb,
    const bf16* __restrict__ vb, const bf16* __restrict__ wvb,
    const float* __restrict__ qnw, const float* __restrict__ knw,
    bf16* __restrict__ Qp, bf16* __restrict__ Kp, bf16* __restrict__ Vt)
{
  __shared__ bf16 smem[36864];
  const int K = 1024;
  const int z = blockIdx.z;
  const bf16 *A, *W;
  if (z == 0)      { A = qb; W = wqb; }
  else if (z == 1) { A = kb; W = wkb; }
  else             { A = vb; W = wvb; }

  const int m0 = blockIdx.y * 128, n0 = blockIdx.x * 256;
  const int t = threadIdx.x;
  const int lane = t & 63, w = t >> 6;
  const int l16 = lane & 15, qd = lane >> 4;
  const int wm = ((w >> 2) & 1) * 64, wn = (w & 3) * 64;

  bf16* As = smem;                 // 3 buffers x 4096 (128 rows x 32 k)
  bf16* Bs = smem + 12288;         // 3 buffers x 8192 (256 rows x 32 k)

  const int p8 = t >> 3;                 // row pair 0..63
  const int vslot = (t & 7) ^ (p8 & 7);
  const int srow = 2 * p8 + (vslot >> 2);
  const int scc = vslot & 3;
  const bf16* ag0 = A + (size_t)(m0 + srow) * K + scc * 8;        // A: 128 rows
  const bf16* wg0 = W + (size_t)(n0 + srow) * K + scc * 8;        // B half 0
  const bf16* wg1 = W + (size_t)(n0 + 128 + srow) * K + scc * 8;  // B half 1
  const int lo0 = t * 8;
  const int lo1 = 4096 + t * 8;

  const int rslot = (((l16 & 1) * 4 + qd) ^ ((l16 >> 1) & 7)) * 8;
  const int abase = (((w >> 2) & 1) * 32 + (l16 >> 1)) * 64 + rslot;
  const int bbase = ((w >> 1) & 1) * 4096 + ((w & 1) * 32 + (l16 >> 1)) * 64 + rslot;

  f32x4_t acc[4][4] = {};

#define STAGEG(k0_, b_)                                  \
  do {                                                   \
    GLD_LDS16(ag0 + (k0_), &As[(b_) * 4096 + lo0]);      \
    GLD_LDS16(wg0 + (k0_), &Bs[(b_) * 8192 + lo0]);      \
    GLD_LDS16(wg1 + (k0_), &Bs[(b_) * 8192 + lo1]);      \
  } while (0)

  STAGEG(0, 0);
  STAGEG(32, 1);

  for (int kk = 0; kk < 32; ++kk) {
    const int cb = kk - (kk / 3) * 3;           // kk % 3
    if (kk < 31) S_WAITCNT_VMCNT(3); else S_WAITCNT_VMCNT(0);
    S_BARRIER();
    if (kk + 2 < 32) {
      const int nb = (kk + 2) - ((kk + 2) / 3) * 3;
      STAGEG((kk + 2) * 32, nb);
    }
    bf16x8_t af[4], bfg[4];
#pragma unroll
    for (int i = 0; i < 4; ++i)
      af[i] = *(const bf16x8_t*)(&As[cb * 4096 + abase + i * 512]);
#pragma unroll
    for (int j = 0; j < 4; ++j)
      bfg[j] = *(const bf16x8_t*)(&Bs[cb * 8192 + bbase + j * 512]);
#pragma unroll
    for (int i = 0; i < 4; ++i)
#pragma unroll
      for (int j = 0; j < 4; ++j)
        acc[i][j] = __builtin_amdgcn_mfma_f32_16x16x32_bf16(af[i], bfg[j], acc[i][j], 0, 0, 0);
  }
#undef STAGEG

  const int h = blockIdx.x * 4 + (w & 3);       // head 0..15 (one per wave)
  const int b = (m0 + wm) >> 11;                // batch

  if (z == 2) {
#pragma unroll
    for (int i = 0; i < 4; ++i) {
      const int sq = ((m0 + wm) & 2047) + i * 16 + qd * 4;
      const int pos = (sq & ~31) + 8 * qd + 4 * (i & 1);
#pragma unroll
      for (int j = 0; j < 4; ++j) {
        const int dk = j * 16 + l16;
        bf16x4_t ov;
#pragma unroll
        for (int r = 0; r < 4; ++r) ov[r] = (bf16)acc[i][j][r];
        *(bf16x4_t*)(Vt + ((size_t)((b * 16 + h) * 64 + dk)) * 2048 + pos) = ov;
      }
    }
    return;
  }

  const float* nw = (z == 0) ? qnw : knw;
  const float osc = (z == 0) ? 0.125f * 1.44269504088896f : 1.0f;
  bf16* Out = (z == 0) ? Qp : Kp;

  float nwv[4];
#pragma unroll
  for (int j = 0; j < 4; ++j) nwv[j] = nw[j * 16 + l16];
  float invf[2];
#pragma unroll
  for (int jj = 0; jj < 2; ++jj) {
    const int d = jj * 16 + l16;
    invf[jj] = __builtin_amdgcn_exp2f(-(float)(2 * d) * (18.93156857f / 64.0f)) * 0.15915494309f;
  }

  __syncthreads();                      // all waves done reading GEMM LDS
  bf16* ep = smem + w * 1152;           // 16 x 72 bf16 wave-private patch

#pragma unroll
  for (int i = 0; i < 4; ++i) {
    const int sbase = ((m0 + wm) & 2047) + i * 16 + qd * 4;
    float ssq[4];
#pragma unroll
    for (int r = 0; r < 4; ++r) {
      ssq[r] = 0.f;
#pragma unroll
      for (int j = 0; j < 4; ++j) ssq[r] += acc[i][j][r] * acc[i][j][r];
    }
#pragma unroll
    for (int off = 1; off < 16; off <<= 1)
#pragma unroll
      for (int r = 0; r < 4; ++r) ssq[r] += __shfl_xor(ssq[r], off);

    float xn[4][4];
#pragma unroll
    for (int r = 0; r < 4; ++r) {
      const float inv = 1.0f / sqrtf(ssq[r] * (1.0f / 64.0f) + 1e-10f);
#pragma unroll
      for (int j = 0; j < 4; ++j) xn[j][r] = acc[i][j][r] * inv * nwv[j];
    }
#pragma unroll
    for (int jj = 0; jj < 2; ++jj) {
#pragma unroll
      for (int r = 0; r < 4; ++r) {
        const int s = sbase + r;
        float rev = (float)s * invf[jj];
        rev = rev - floorf(rev);
        const float cv = __builtin_amdgcn_cosf(rev);
        const float sv = __builtin_amdgcn_sinf(rev);
        const float o1 = (xn[jj][r] * cv - xn[jj + 2][r] * sv) * osc;
        const float o2 = (xn[jj + 2][r] * cv + xn[jj][r] * sv) * osc;
        const int prow = qd * 4 + r;
        ep[prow * 72 + jj * 16 + l16] = (bf16)o1;
        ep[prow * 72 + 32 + jj * 16 + l16] = (bf16)o2;
      }
    }
    const int sg = ((m0 + wm) & 2047) + i * 16 + l16;
    const bf16x8_t t0 = *(const bf16x8_t*)(ep + l16 * 72 + qd * 16);
    const bf16x8_t t1 = *(const bf16x8_t*)(ep + l16 * 72 + qd * 16 + 8);
    bf16* gb = Out + ((size_t)(b * 16 + h) * 2048 + sg) * 64 + qd * 16;
    *(bf16x8_t*)(gb) = t0;
    *(bf16x8_t*)(gb + 8) = t1;
  }
}

// ---------------------------------------------------------------------------
// R21: Output projection retiled 128x128 -> 128x64 (256 thr, 4 waves 2Mx2N,
// wave = 64x32, acc[4][2]). Rationale: old grid (8,32) = 256 WGs = 1 WG/CU
// = ZERO workgroup TLP — same hole R19 fixed on qkv. New grid (16,32) =
// 512 WGs -> 2 WG/CU; LDS 3x(A 4096 + B 2048) = 36KB. A staging/reader =
// gemm_core two-half code verbatim; B = single 64-row SLOT8 half
// (pair = (w>>1)*16 + j*8 + (l16>>1); ^(p&7) key = (l16>>1)&7, invariant).
// 3 gloads/thread -> vmcnt(3) distance-2 (R19 ledger). Same K-order fp32
// accumulation -> numerics unchanged. Chunked XCD swizzle, chunk=64.
// ---------------------------------------------------------------------------
__global__ __launch_bounds__(256) void gemm_out_k(
    const bf16* __restrict__ Ob, const bf16* __restrict__ wob, float* __restrict__ out)
{
  __shared__ bf16 smem[18432];
  const int K = 1024;
  const int N = 1024;

  const int orig = blockIdx.x + 16 * blockIdx.y;
  const int wgid = (orig & 7) * 64 + (orig >> 3);
  const int bx = wgid & 15, by = wgid >> 4;

  const int m0 = by * 128, n0 = bx * 64;
  const int t = threadIdx.x;
  const int lane = t & 63, w = t >> 6;
  const int l16 = lane & 15, qd = lane >> 4;
  const int wm = (w & 1) * 64, wn = (w >> 1) * 32;

  bf16* As = smem;                 // 3 buffers x 4096 (128 rows x 32 k)
  bf16* Bs = smem + 12288;         // 3 buffers x 2048 (64 rows x 32 k)

  const int p8 = t >> 3;                 // row pair 0..31
  const int vslot = (t & 7) ^ (p8 & 7);
  const int srow = 2 * p8 + (vslot >> 2);
  const int scc = vslot & 3;
  const bf16* ag0 = Ob + (size_t)(m0 + srow) * K + scc * 8;       // A rows 0-63
  const bf16* ag1 = Ob + (size_t)(m0 + 64 + srow) * K + scc * 8;  // A rows 64-127
  const bf16* wg0 = wob + (size_t)(n0 + srow) * K + scc * 8;      // B rows 0-63
  const int lo0 = t * 8;
  const int lo1 = 2048 + t * 8;

  const int rslot = (((l16 & 1) * 4 + qd) ^ ((l16 >> 1) & 7)) * 8;
  const int abase = (wm >> 6) * 2048 + (l16 >> 1) * 64 + rslot;
  const int bbase = ((w >> 1) * 16 + (l16 >> 1)) * 64 + rslot;

  f32x4_t acc[4][2] = {};

#define STAGEG(k0_, b_)                                  \
  do {                                                   \
    GLD_LDS16(ag0 + (k0_), &As[(b_) * 4096 + lo0]);      \
    GLD_LDS16(ag1 + (k0_), &As[(b_) * 4096 + lo1]);      \
    GLD_LDS16(wg0 + (k0_), &Bs[(b_) * 2048 + lo0]);      \
  } while (0)

  STAGEG(0, 0);
  STAGEG(32, 1);

  for (int kk = 0; kk < 32; ++kk) {
    const int cb = kk - (kk / 3) * 3;           // kk % 3
    if (kk < 31) S_WAITCNT_VMCNT(3); else S_WAITCNT_VMCNT(0);
    S_BARRIER();
    if (kk + 2 < 32) {
      const int nb = (kk + 2) - ((kk + 2) / 3) * 3;
      STAGEG((kk + 2) * 32, nb);
    }
    bf16x8_t af[4], bfg[2];
#pragma unroll
    for (int i = 0; i < 4; ++i)
      af[i] = *(const bf16x8_t*)(&As[cb * 4096 + abase + i * 512]);
#pragma unroll
    for (int j = 0; j < 2; ++j)
      bfg[j] = *(const bf16x8_t*)(&Bs[cb * 2048 + bbase + j * 512]);
#pragma unroll
    for (int i = 0; i < 4; ++i)
#pragma unroll
      for (int j = 0; j < 2; ++j)
        acc[i][j] = __builtin_amdgcn_mfma_f32_16x16x32_bf16(af[i], bfg[j], acc[i][j], 0, 0, 0);
  }
#undef STAGEG

  __syncthreads();
  float* epf = (float*)smem + w * 1088;   // 16 x 68 f32 wave-private patch

#pragma unroll
  for (int i = 0; i < 4; ++i) {
#pragma unroll
    for (int j = 0; j < 2; ++j)
#pragma unroll
      for (int r = 0; r < 4; ++r)
        epf[(qd * 4 + r) * 68 + j * 16 + l16] = acc[i][j][r];
    const int row = m0 + wm + i * 16 + l16;
    const f32x4_t v0 = *(const f32x4_t*)(epf + l16 * 68 + qd * 8);
    const f32x4_t v1 = *(const f32x4_t*)(epf + l16 * 68 + qd * 8 + 4);
    float* gb = out + (size_t)row * N + n0 + wn + qd * 8;
    *(f32x4_t*)(gb) = v0;
    *(f32x4_t*)(gb + 4) = v1;
  }
}

// ---------------------------------------------------------------------------
// Causal flash attention — KVBLK=64, T1 chunked swizzle, R17 complementary-qt
// CU pairing, T5 setprio, R20 4-buffer/distance-3 prefetch (kept: 203.3us).
// ---------------------------------------------------------------------------
__global__ __launch_bounds__(512) void flash_attn(
    const bf16* __restrict__ Qp, const bf16* __restrict__ Kp,
    const bf16* __restrict__ Vt, bf16* __restrict__ O)
{
  const int S = 2048;

  const int orig = blockIdx.x + 16 * blockIdx.y;
  const int wgid = (orig & 7) * 64 + (orig >> 3);
  const int u = wgid & 63;
  const int bh = wgid >> 4;                    // 4 bh per XCD chunk
  const int x = u & 15;
  const int qt = (u < 32) ? (15 - x) : x;      // complementary pairing

  const int t = threadIdx.x;
  const int lane = t & 63, w = t >> 6;
  const int l16 = lane & 15, qd = lane >> 4;

  __shared__ bf16 Ks[4][64 * 64];
  __shared__ bf16 Vs[4][64 * 64];

  const int qrow = qt * 128 + w * 16 + l16;
  const bf16* qbase = Qp + ((size_t)bh * S + qrow) * 64 + qd * 8;
  const bf16x8_t qf0 = *(const bf16x8_t*)qbase;
  const bf16x8_t qf1 = *(const bf16x8_t*)(qbase + 32);

  f32x4_t o_acc[4] = {};
  float l_i = 0.f;

  const int srow = t >> 3;
  const int scol = ((t & 7) ^ (srow & 7)) * 8;
  const bf16* kg = Kp + ((size_t)bh * S + srow) * 64 + scol;
  const bf16* vg = Vt + ((size_t)(bh * 64 + srow)) * S + scol;
  const int lo = w * 512;

  const int sw = l16 & 7;

#define STAGE(kt_, b_)                                 \
  do {                                                 \
    GLD_LDS16(kg + (size_t)(kt_) * 4096, &Ks[b_][lo]); \
    GLD_LDS16(vg + (kt_) * 64, &Vs[b_][lo]);           \
  } while (0)

  const int ktmax = 2 * qt + 1;                // >= 1 always
  STAGE(0, 0);
  STAGE(1, 1);
  if (ktmax >= 2) STAGE(2, 2);

  for (int kt = 0; kt <= ktmax; ++kt) {
    const int cb = kt & 3;
    if (kt + 2 <= ktmax)      S_WAITCNT_VMCNT(4);
    else if (kt < ktmax)      S_WAITCNT_VMCNT(2);
    else                      S_WAITCNT_VMCNT(0);
    S_BARRIER();
    if (kt + 3 <= ktmax) {
      STAGE(kt + 3, (kt + 3) & 3);
    }

    if (kt == ktmax && w < 4) continue;

    f32x4_t sf[4];
    __builtin_amdgcn_s_setprio(1);
#pragma unroll
    for (int nt = 0; nt < 4; ++nt) {
      sf[nt][0] = -12.f; sf[nt][1] = -12.f; sf[nt][2] = -12.f; sf[nt][3] = -12.f;
      const bf16x8_t kf0 = *(const bf16x8_t*)(&Ks[cb][(nt * 16 + l16) * 64 + ((0 + qd) ^ sw) * 8]);
      const bf16x8_t kf1 = *(const bf16x8_t*)(&Ks[cb][(nt * 16 + l16) * 64 + ((4 + qd) ^ sw) * 8]);
      sf[nt] = __builtin_amdgcn_mfma_f32_16x16x32_bf16(kf0, qf0, sf[nt], 0, 0, 0);
      sf[nt] = __builtin_amdgcn_mfma_f32_16x16x32_bf16(kf1, qf1, sf[nt], 0, 0, 0);
    }
    __builtin_amdgcn_s_setprio(0);

    if (kt >= ktmax - 1) {
      const int kofs = (kt - 2 * qt) * 64;
      const int q_local = w * 16 + l16;
#pragma unroll
      for (int nt = 0; nt < 4; ++nt)
#pragma unroll
        for (int r = 0; r < 4; ++r)
          if (kofs + nt * 16 + qd * 4 + r > q_local) sf[nt][r] = -100.f;
    }

    bf16x4_t pb[4];
#pragma unroll
    for (int nt = 0; nt < 4; ++nt)
#pragma unroll
      for (int r = 0; r < 4; ++r) {
        const float p = __builtin_amdgcn_exp2f(sf[nt][r]);
        l_i += p;
        pb[nt][r] = (bf16)p;
      }

    __builtin_amdgcn_s_setprio(1);
#pragma unroll
    for (int nt2 = 0; nt2 < 2; ++nt2) {
      bf16x8_t pf;
#pragma unroll
      for (int r = 0; r < 4; ++r) { pf[r] = pb[2 * nt2][r]; pf[4 + r] = pb[2 * nt2 + 1][r]; }
#pragma unroll
      for (int dt = 0; dt < 4; ++dt) {
        const int row = dt * 16 + l16;
        const bf16x8_t vf =
            *(const bf16x8_t*)(&Vs[cb][row * 64 + ((4 * nt2 + qd) ^ sw) * 8]);
        o_acc[dt] = __builtin_amdgcn_mfma_f32_16x16x32_bf16(vf, pf, o_acc[dt], 0, 0, 0);
      }
    }
    __builtin_amdgcn_s_setprio(0);
  }
#undef STAGE

  l_i += __shfl_xor(l_i, 16);
  l_i += __shfl_xor(l_i, 32);

  const int b = bh >> 4, h = bh & 15;
  const float inv_l = 1.0f / l_i;
  const int qg = qt * 128 + w * 16 + l16;
#pragma unroll
  for (int dt = 0; dt < 4; ++dt) {
    bf16x4_t ov;
#pragma unroll
    for (int r = 0; r < 4; ++r) ov[r] = (bf16)(o_acc[dt][r] * inv_l);
    *(bf16x4_t*)(O + ((size_t)(b * S + qg)) * 1024 + h * 64 + dt * 16 + qd * 4) = ov;
  }
}

// ---------------------------------------------------------------------------
extern "C" void kernel_launch(void* const* d_in, const int* in_sizes, int n_in,
                              void* d_out, int out_size, void* d_ws, size_t ws_size,
                              hipStream_t stream)
{
  const float* q   = (const float*)d_in[0];
  const float* k   = (const float*)d_in[1];
  const float* v   = (const float*)d_in[2];
  const float* wq  = (const float*)d_in[3];
  const float* wk  = (const float*)d_in[4];
  const float* wv  = (const float*)d_in[5];
  const float* wo  = (const float*)d_in[6];
  const float* qnw = (const float*)d_in[7];
  const float* knw = (const float*)d_in[8];

  char* ws = (char*)d_ws;
  const size_t MB = 1u << 20;
  bf16* qb  = (bf16*)(ws + 0 * MB);    // dead after gemm_qkv
  bf16* kb  = (bf16*)(ws + 8 * MB);
  bf16* vb  = (bf16*)(ws + 16 * MB);
  bf16* wqb = (bf16*)(ws + 24 * MB);
  bf16* wkb = (bf16*)(ws + 26 * MB);
  bf16* wvb = (bf16*)(ws + 28 * MB);
  bf16* wob = (bf16*)(ws + 30 * MB);
  bf16* Qp  = (bf16*)(ws + 32 * MB);
  bf16* Kp  = (bf16*)(ws + 40 * MB);
  bf16* Vtr = (bf16*)(ws + 48 * MB);
  bf16* Oattn = qb;                    // alias: qb dead once flash starts

  cvt_kernel<<<dim3(1024, 7), 256, 0, stream>>>(q, k, v, wq, wk, wv, wo,
                                                qb, kb, vb, wqb, wkb, wvb, wob);
  gemm_qkv<<<dim3(4, 32, 3), 512, 0, stream>>>(qb, wqb, kb, wkb, vb, wvb,
                                               qnw, knw, Qp, Kp, Vtr);
  flash_attn<<<dim3(16, 32), 512, 0, stream>>>(Qp, Kp, Vtr, Oattn);
  gemm_out_k<<<dim3(16, 32), 256, 0, stream>>>(Oattn, wob, (float*)d_out);
}